// Round 8
// baseline (139.378 us; speedup 1.0000x reference)
//
#include <hip/hip_runtime.h>

// Conv2d int32 (values fit int8) via implicit GEMM, v14: weights via L2, x-only LDS.
// x8: [chunk8][b16][row58][slot58][32B] (halo zeroed, granule parity (g+(slot>>2))&1)
// w8: [cotile4][chunk8][tap9][co64][32B]  <-- NEW layout, no parity swizzle.
// v14 = v13 with the A (weight) operand moved out of LDS: fragments are read
// directly from L2-resident w8 with perfectly coalesced global_load_dwordx4
// (lane(n,gq) reads tap*2048 + n*32 + gq*16 -> wave covers contiguous 1024B).
// All 18 A-fragments of chunk c load into regs BEFORE stage(c+1) is issued
// (FIFO vmcnt: A-use never drains staging). LDS reads/tap drop 6->4 (-33%),
// staging halves (5 gll/thread), LDS = 2x20,480 B. Per-CU chunk-pair cost:
// LDS ~3,800 cyc < MFMA 5,266 -> matrix pipe finally the single critical path.

typedef int v4i  __attribute__((ext_vector_type(4)));
typedef int v16i __attribute__((ext_vector_type(16)));

#define X8_ROWSTRIDE 1856                 // 58 slots * 32 B
#define X8_IMGSTRIDE 107648               // 58 rows * 1856
#define X8_BYTES     13778944             // 128 images (8 chunks x 16 b)
#define W8_CHUNK     18432                // 9 tap * 64 co * 32 B
#define XBUF         20480                // 1,280 granules (10 rows used = 1,160)

typedef const __attribute__((address_space(1))) unsigned char* gptr_t;
typedef __attribute__((address_space(3))) unsigned char* lptr_t;

__device__ __forceinline__ void gll(const unsigned char* g, unsigned char* l) {
  __builtin_amdgcn_global_load_lds((gptr_t)g, (lptr_t)l, 16, 0, 0);
}

__device__ __forceinline__ int pack4(const int* p, int stride) {
  return (p[0] & 255) | ((p[stride] & 255) << 8) |
         ((p[2 * stride] & 255) << 16) | ((p[3 * stride] & 255) << 24);
}

// ---- fused prepass ----
// blocks [0,784): x interior (unchanged). [784,1012): halo zeros (unchanged).
// blocks [1012,1156): w pack into NEW [cotile][chunk][tap][co][32B] layout.
__global__ __launch_bounds__(256)
void pack_all(const int* __restrict__ x, const int* __restrict__ wgt,
              unsigned char* __restrict__ ws8) {
  const int blk = blockIdx.x;
  if (blk < 784) {
    const int gid = blk * 256 + threadIdx.x;
    const int srcg = gid & 1;
    int t = gid >> 1;
    const int sq = t % 14;  t /= 14;      // slots 4sq+1 .. 4sq+4, iw 4sq .. 4sq+3
    const int row = t % 56 + 1;           // 1..56
    const int cb  = t / 56;               // chunk*16 + b
    const int chunk = cb >> 4, b = cb & 15;
    const int ci0 = chunk * 32 + srcg * 16;
    const int* src = x + (b * 256 + ci0) * 3136 + (row - 1) * 56 + 4 * sq;
    v4i L[16];
    #pragma unroll
    for (int ch = 0; ch < 16; ++ch) L[ch] = *(const v4i*)(src + ch * 3136);
    unsigned char* dstrow = ws8 + cb * X8_IMGSTRIDE + row * X8_ROWSTRIDE;
    #pragma unroll
    for (int j = 0; j < 4; ++j) {
      const int slot = 4 * sq + 1 + j;
      v4i g;
      #pragma unroll
      for (int d = 0; d < 4; ++d)
        g[d] = (L[4 * d][j] & 255) | ((L[4 * d + 1][j] & 255) << 8) |
               ((L[4 * d + 2][j] & 255) << 16) | ((L[4 * d + 3][j] & 255) << 24);
      const int p = (srcg + (slot >> 2)) & 1;   // inverse of srcg=(p+(slot>>2))&1
      *(v4i*)(dstrow + slot * 32 + p * 16) = g;
    }
  } else if (blk < 1012) {
    const int g2 = (blk - 784) * 256 + threadIdx.x;   // 58,368 granules
    const int cb = g2 / 456;
    const int r  = g2 - cb * 456;
    int off;
    if (r < 232) {                       // rows 0 and 57, all 58 slots x 2 granules
      const int row = r < 116 ? 0 : 57;
      const int rr = r % 116;
      off = row * X8_ROWSTRIDE + (rr >> 1) * 32 + (rr & 1) * 16;
    } else {                             // rows 1..56, slots 0 and 57
      const int r2 = r - 232;            // 0..223
      const int row = (r2 >> 2) + 1;
      const int slot = (r2 & 2) ? 57 : 0;
      off = row * X8_ROWSTRIDE + slot * 32 + (r2 & 1) * 16;
    }
    *(v4i*)(ws8 + cb * X8_IMGSTRIDE + off) = (v4i){0, 0, 0, 0};
  } else {
    const int gw = (blk - 1012) * 256 + threadIdx.x;  // 36,864 granules exact
    const int p = gw & 1;                // K-half (ci sub-block of 16)
    int t = gw >> 1;                     // t = ((cotile*8+chunk)*9+tap)*64 + co
    const int co = t & 63;
    int u = t >> 6;                      // 0..287
    const int tap = u % 9;
    const int cc = u / 9;                // chunk + 8*cotile
    const int chunk = cc & 7, cotile = cc >> 3;
    const int ci0 = chunk * 32 + p * 16;
    const int* src = wgt + ((cotile * 64 + co) * 256 + ci0) * 9 + tap;
    v4i v = (v4i){pack4(src, 9), pack4(src + 36, 9),
                  pack4(src + 72, 9), pack4(src + 108, 9)};
    *(v4i*)(ws8 + X8_BYTES + t * 32 + p * 16) = v;   // contiguous, coalesced
  }
}

// ---- stage one x chunk (20,480 B = 1,280 granules) into buffer buf ----
// Exactly 5 x 16B global_load_lds per thread (256 threads), fully uniform.
__device__ __forceinline__ void stage_chunk(const unsigned char* xg,
                                            unsigned char* ldsb, int c, int buf,
                                            int tid) {
  const unsigned char* xsrc = xg + c * (16 * X8_IMGSTRIDE);
  unsigned char* xdst = ldsb + buf * XBUF;
  #pragma unroll
  for (int i = 0; i < 5; ++i) {
    const int o = (tid + i * 256) * 16;
    gll(xsrc + o, xdst + o);
  }
}

// Load B-fragment set for tap T (compile-time after unroll) into slot S.
#define LOADB(T, S)                                                       \
  do {                                                                    \
    const int kw_ = (T) % 3;                                              \
    const unsigned char* xr_ = xs + rbase + ((T) / 3) * X8_ROWSTRIDE;     \
    fb[S][0] = *(const v4i*)(xr_ + boff[kw_][0]);                         \
    fb[S][1] = *(const v4i*)(xr_ + boff[kw_][1]);                         \
    fb[S][2] = *(const v4i*)(xr_ + boff[kw_][2]);                         \
    fb[S][3] = *(const v4i*)(xr_ + boff[kw_][3]);                         \
  } while (0)

// ---- main kernel: A from L2 (regs), B via LDS, 2 buffers, 2 blocks/CU ----
__global__ __launch_bounds__(256, 2)
void conv_main(const unsigned char* __restrict__ ws8, const int* __restrict__ bias,
               int* __restrict__ out) {
  __shared__ __align__(16) unsigned char lds[2 * XBUF];   // 40,960 B
  __shared__ int bls[64];

  const int tid = threadIdx.x, lane = tid & 63, wv = tid >> 6;  // wv 0..3
  const int n = lane & 31, gq = lane >> 5;
  const int tc = blockIdx.y;             // co tile of 64
  const int hb = blockIdx.x;             // hg*16 + b
  const int hg = hb >> 4, b = hb & 15;   // hg 0..6
  const int h0 = hg * 8;

  if (tid < 64) {
    bls[tid] = bias[tc * 64 + tid];
    asm volatile("s_waitcnt lgkmcnt(0)" ::: "memory");
  }

  const int aoff = n * 32 + gq * 16;     // coalesced A-fragment offset
  int boff[3][4];
  #pragma unroll
  for (int kw = 0; kw < 3; ++kw)
    #pragma unroll
    for (int bt = 0; bt < 4; ++bt) {
      int slot = bt * 16 + (n & 15) + kw;
      if (slot > 57) slot = 57;
      boff[kw][bt] = slot * 32 + (((gq + (slot >> 2)) & 1) << 4);
    }
  const int rbase = (2 * wv + (n >> 4)) * X8_ROWSTRIDE;   // rows 0..7 of stage

  v16i acc[2][4];
  #pragma unroll
  for (int i = 0; i < 2; ++i)
    #pragma unroll
    for (int j = 0; j < 4; ++j)
      acc[i][j] = (v16i){0,0,0,0,0,0,0,0,0,0,0,0,0,0,0,0};

  const unsigned char* wg = ws8 + X8_BYTES + tc * (8 * W8_CHUNK);
  const unsigned char* xg = ws8 + b * X8_IMGSTRIDE + h0 * X8_ROWSTRIDE;

  stage_chunk(xg, lds, 0, 0, tid);
  int buf = 0;
  #pragma unroll 1
  for (int c = 0; c < 8; ++c) {
    // stage(c) issued one chunk ago; its latency hid under compute(c-1).
    asm volatile("s_waitcnt vmcnt(0)" ::: "memory");
    __builtin_amdgcn_s_barrier();
    asm volatile("" ::: "memory");
    // A-fragments for chunk c: 18 coalesced global loads (L2-resident w8),
    // issued BEFORE stage(c+1) so tap-wise A-use never drains staging (FIFO).
    const unsigned char* wgc = wg + c * W8_CHUNK;
    v4i A0[9], A1[9];
    #pragma unroll
    for (int t = 0; t < 9; ++t) {
      A0[t] = *(const v4i*)(wgc + t * 2048 + aoff);          // co 0..31
      A1[t] = *(const v4i*)(wgc + t * 2048 + 1024 + aoff);   // co 32..63
    }
    if (c < 7) stage_chunk(xg, lds, c + 1, buf ^ 1, tid);    // overlaps compute(c)
    {
      const unsigned char* xs = lds + buf * XBUF;
      v4i fb[2][4];
      LOADB(0, 0);                       // preload tap 0 B-fragments
      __builtin_amdgcn_sched_group_barrier(0x100, 4, 0);     // DS_READ x4
      #pragma unroll
      for (int tap = 0; tap < 9; ++tap) {
        const int cur = tap & 1, nxt = cur ^ 1;
        if (tap < 8) {
          LOADB(tap + 1, nxt);           // issue next-tap B reads FIRST
          __builtin_amdgcn_sched_group_barrier(0x100, 4, 0); // DS_READ x4 (t+1)
        }
        #pragma unroll
        for (int bt = 0; bt < 4; ++bt) {
          acc[0][bt] = __builtin_amdgcn_mfma_i32_32x32x32_i8(A0[tap], fb[cur][bt], acc[0][bt], 0, 0, 0);
          acc[1][bt] = __builtin_amdgcn_mfma_i32_32x32x32_i8(A1[tap], fb[cur][bt], acc[1][bt], 0, 0, 0);
        }
        __builtin_amdgcn_sched_group_barrier(0x008, 8, 0);   // MFMA x8 (tap t)
      }
    }
    buf ^= 1;
  }

  const int h = h0 + 2 * wv + (n >> 4);   // <= 55 always
  const int wbase = lane & 15;
  #pragma unroll
  for (int ct = 0; ct < 2; ++ct) {
    #pragma unroll
    for (int r = 0; r < 16; ++r) {
      const int co64 = ct * 32 + (r & 3) + 8 * (r >> 2) + 4 * gq;
      const int bv = bls[co64];
      int* orow = out + ((b * 256 + tc * 64 + co64) * 56 + h) * 56;
      #pragma unroll
      for (int bt = 0; bt < 4; ++bt) {
        const int w0 = bt * 16 + wbase;
        if (w0 < 56) orow[w0] = acc[ct][bt][r] + bv;
      }
    }
  }
}

extern "C" void kernel_launch(void* const* d_in, const int* in_sizes, int n_in,
                              void* d_out, int out_size, void* d_ws, size_t ws_size,
                              hipStream_t stream) {
  const int* x    = (const int*)d_in[0];
  const int* w    = (const int*)d_in[1];
  const int* bias = (const int*)d_in[2];
  unsigned char* ws8 = (unsigned char*)d_ws;   // x8 then w8 (~14.4 MB)
  hipLaunchKernelGGL(pack_all, dim3(1156), dim3(256), 0, stream, x, w, ws8);
  hipLaunchKernelGGL(conv_main, dim3(112, 4, 1), dim3(256), 0, stream,
                     ws8, bias, (int*)d_out);
}

// Round 9
// 130.385 us; speedup vs baseline: 1.0690x; 1.0690x over previous
//
#include <hip/hip_runtime.h>

// Conv2d int32 (values fit int8) via implicit GEMM, v15: v13 + de-phasing.
// x8: [chunk8][b16][row58][slot58][32B] (halo zeroed, granule parity (g+(slot>>2))&1)
// w8: [cotile4][chunk8][co64][tap9][32B] (granule parity (g+(co>>2))&1)
// v15 = v13 (best: 130.2us; 4-wave/256-thr blocks, 64co x 8rows, 2 LDS bufs,
// 2 blocks/CU, tap-level reg pipeline) + two de-phasing levers:
// (1) chunk-order rotation c=(i+phase)&7, phase=(hb&32)?4:0 — co-resident
//     blocks (~k,k+256: hb differs by 32) run half-sequence out of phase so
//     one block's MFMA covers the other's stage/drain (int K-sum is order-
//     independent; tc-partners share hb -> same phase -> x L2-reuse kept).
// (2) T5 s_setprio(1) around each 8-MFMA group — with role diversity from
//     (1), MFMA-ready waves win issue arbitration over read-bursting waves.
// v14 (A via per-wave L2 loads) regressed: A-fetch traffic x8 waves + per-tap
// vmcnt waits on the MFMA path. Reverted.

typedef int v4i  __attribute__((ext_vector_type(4)));
typedef int v16i __attribute__((ext_vector_type(16)));

#define X8_ROWSTRIDE 1856                 // 58 slots * 32 B
#define X8_IMGSTRIDE 107648               // 58 rows * 1856
#define X8_BYTES     13778944             // 128 images (8 chunks x 16 b)
#define W8_CHUNK     18432                // 64 co * 9 tap * 32 B
#define WBUF         18432
#define XBUF         20480                // 1,280 granules (10 rows used = 1,160)
#define LBUF         38912                // WBUF + XBUF

typedef const __attribute__((address_space(1))) unsigned char* gptr_t;
typedef __attribute__((address_space(3))) unsigned char* lptr_t;

__device__ __forceinline__ void gll(const unsigned char* g, unsigned char* l) {
  __builtin_amdgcn_global_load_lds((gptr_t)g, (lptr_t)l, 16, 0, 0);
}

__device__ __forceinline__ int pack4(const int* p, int stride) {
  return (p[0] & 255) | ((p[stride] & 255) << 8) |
         ((p[2 * stride] & 255) << 16) | ((p[3 * stride] & 255) << 24);
}

// ---- fused prepass (identical to v9/v13) ----
__global__ __launch_bounds__(256)
void pack_all(const int* __restrict__ x, const int* __restrict__ wgt,
              unsigned char* __restrict__ ws8) {
  const int blk = blockIdx.x;
  if (blk < 784) {
    const int gid = blk * 256 + threadIdx.x;
    const int srcg = gid & 1;
    int t = gid >> 1;
    const int sq = t % 14;  t /= 14;      // slots 4sq+1 .. 4sq+4, iw 4sq .. 4sq+3
    const int row = t % 56 + 1;           // 1..56
    const int cb  = t / 56;               // chunk*16 + b
    const int chunk = cb >> 4, b = cb & 15;
    const int ci0 = chunk * 32 + srcg * 16;
    const int* src = x + (b * 256 + ci0) * 3136 + (row - 1) * 56 + 4 * sq;
    v4i L[16];
    #pragma unroll
    for (int ch = 0; ch < 16; ++ch) L[ch] = *(const v4i*)(src + ch * 3136);
    unsigned char* dstrow = ws8 + cb * X8_IMGSTRIDE + row * X8_ROWSTRIDE;
    #pragma unroll
    for (int j = 0; j < 4; ++j) {
      const int slot = 4 * sq + 1 + j;
      v4i g;
      #pragma unroll
      for (int d = 0; d < 4; ++d)
        g[d] = (L[4 * d][j] & 255) | ((L[4 * d + 1][j] & 255) << 8) |
               ((L[4 * d + 2][j] & 255) << 16) | ((L[4 * d + 3][j] & 255) << 24);
      const int p = (srcg + (slot >> 2)) & 1;   // inverse of srcg=(p+(slot>>2))&1
      *(v4i*)(dstrow + slot * 32 + p * 16) = g;
    }
  } else if (blk < 1012) {
    const int g2 = (blk - 784) * 256 + threadIdx.x;   // 58,368 granules
    const int cb = g2 / 456;
    const int r  = g2 - cb * 456;
    int off;
    if (r < 232) {                       // rows 0 and 57, all 58 slots x 2 granules
      const int row = r < 116 ? 0 : 57;
      const int rr = r % 116;
      off = row * X8_ROWSTRIDE + (rr >> 1) * 32 + (rr & 1) * 16;
    } else {                             // rows 1..56, slots 0 and 57
      const int r2 = r - 232;            // 0..223
      const int row = (r2 >> 2) + 1;
      const int slot = (r2 & 2) ? 57 : 0;
      off = row * X8_ROWSTRIDE + slot * 32 + (r2 & 1) * 16;
    }
    *(v4i*)(ws8 + cb * X8_IMGSTRIDE + off) = (v4i){0, 0, 0, 0};
  } else {
    const int gw = (blk - 1012) * 256 + threadIdx.x;  // 36,864 granules exact
    const int p = gw & 1;
    int t = gw >> 1;
    const int tap = t % 9;  t /= 9;
    const int co = t & 63;
    const int tcc = t >> 6;              // 0..287: chunk 0..7, cotile 0..3
    const int chunk = tcc & 7, cotile = tcc >> 3;
    const int srcg = (p + (co >> 2)) & 1;   // inverse of p=(srcg+(co>>2))&1
    const int ci0 = chunk * 32 + srcg * 16;
    const int* src = wgt + ((cotile * 64 + co) * 256 + ci0) * 9 + tap;
    v4i v = (v4i){pack4(src, 9), pack4(src + 36, 9),
                  pack4(src + 72, 9), pack4(src + 108, 9)};
    *(v4i*)(ws8 + X8_BYTES + (t * 9 + tap) * 32 + p * 16) = v;
  }
}

// ---- stage one chunk (w 18,432 B + x 20,480 B = 2,432 granules) into buf ----
__device__ __forceinline__ void stage_chunk(const unsigned char* wg,
                                            const unsigned char* xg,
                                            unsigned char* ldsb, int c, int buf,
                                            int tid) {
  const unsigned char* wsrc = wg + c * W8_CHUNK;
  const unsigned char* xsrc = xg + c * (16 * X8_IMGSTRIDE);
  unsigned char* wdst = ldsb + buf * LBUF;
  unsigned char* xdst = wdst + WBUF;
  #pragma unroll
  for (int i = 0; i < 4; ++i) {          // w granules [0,1024)
    const int o = (tid + i * 256) * 16;
    gll(wsrc + o, wdst + o);
  }
  if (tid < 128) {                       // w granules [1024,1152)
    const int o = (1024 + tid) * 16;
    gll(wsrc + o, wdst + o);
  } else {                               // x granules [0,128)
    const int o = (tid - 128) * 16;
    gll(xsrc + o, xdst + o);
  }
  #pragma unroll
  for (int i = 5; i < 9; ++i) {          // x granules [128,1152)
    const int o = (tid + i * 256 - 1152) * 16;
    gll(xsrc + o, xdst + o);
  }
  if (tid < 128) {                       // x granules [1152,1280)
    const int o = (1152 + tid) * 16;
    gll(xsrc + o, xdst + o);
  }
}

// Load fragment set for tap T (compile-time after unroll) into slot S.
#define LOADTAP(T, S)                                                     \
  do {                                                                    \
    const int kh_ = (T) / 3, kw_ = (T) % 3;                               \
    const unsigned char* xr_ = xs + rbase + kh_ * X8_ROWSTRIDE;           \
    fa0[S] = *(const v4i*)(wls + abase + (T) * 32);                       \
    fa1[S] = *(const v4i*)(wls + 9216 + abase + (T) * 32);                \
    fb[S][0] = *(const v4i*)(xr_ + boff[kw_][0]);                         \
    fb[S][1] = *(const v4i*)(xr_ + boff[kw_][1]);                         \
    fb[S][2] = *(const v4i*)(xr_ + boff[kw_][2]);                         \
    fb[S][3] = *(const v4i*)(xr_ + boff[kw_][3]);                         \
  } while (0)

// ---- main kernel: 4 waves, 64 co x 8 rows, 2 buffers, 2 blocks/CU ----
__global__ __launch_bounds__(256, 2)
void conv_main(const unsigned char* __restrict__ ws8, const int* __restrict__ bias,
               int* __restrict__ out) {
  __shared__ __align__(16) unsigned char lds[2 * LBUF];   // 77,824 B
  __shared__ int bls[64];

  const int tid = threadIdx.x, lane = tid & 63, wv = tid >> 6;  // wv 0..3
  const int n = lane & 31, gq = lane >> 5;
  const int tc = blockIdx.y;             // co tile of 64
  const int hb = blockIdx.x;             // hg*16 + b
  const int hg = hb >> 4, b = hb & 15;   // hg 0..6
  const int h0 = hg * 8;
  const int phase = (hb & 32) ? 4 : 0;   // de-phase co-resident blocks

  if (tid < 64) {
    bls[tid] = bias[tc * 64 + tid];
    asm volatile("s_waitcnt lgkmcnt(0)" ::: "memory");
  }

  const int abase = n * 288 + (((gq + (n >> 2)) & 1) << 4);
  int boff[3][4];
  #pragma unroll
  for (int kw = 0; kw < 3; ++kw)
    #pragma unroll
    for (int bt = 0; bt < 4; ++bt) {
      int slot = bt * 16 + (n & 15) + kw;
      if (slot > 57) slot = 57;
      boff[kw][bt] = slot * 32 + (((gq + (slot >> 2)) & 1) << 4);
    }
  const int rbase = (2 * wv + (n >> 4)) * X8_ROWSTRIDE;   // rows 0..7 of stage

  v16i acc[2][4];
  #pragma unroll
  for (int i = 0; i < 2; ++i)
    #pragma unroll
    for (int j = 0; j < 4; ++j)
      acc[i][j] = (v16i){0,0,0,0,0,0,0,0,0,0,0,0,0,0,0,0};

  const unsigned char* wg = ws8 + X8_BYTES + tc * (8 * W8_CHUNK);
  const unsigned char* xg = ws8 + b * X8_IMGSTRIDE + h0 * X8_ROWSTRIDE;

  stage_chunk(wg, xg, lds, phase, 0, tid);
  int buf = 0;
  #pragma unroll 1
  for (int i = 0; i < 8; ++i) {
    // stage(seq(i)) was issued before the previous barrier; latency hid
    // under compute(seq(i-1)), so this drain is near-free.
    asm volatile("s_waitcnt vmcnt(0)" ::: "memory");
    __builtin_amdgcn_s_barrier();
    asm volatile("" ::: "memory");
    if (i < 7) stage_chunk(wg, xg, lds, (i + 1 + phase) & 7, buf ^ 1, tid);
    {
      const unsigned char* wls = lds + buf * LBUF;
      const unsigned char* xs  = wls + WBUF;
      v4i fa0[2], fa1[2], fb[2][4];
      LOADTAP(0, 0);                      // preload tap 0
      __builtin_amdgcn_sched_group_barrier(0x100, 6, 0);   // DS_READ x6 (tap 0)
      #pragma unroll
      for (int tap = 0; tap < 9; ++tap) {
        const int cur = tap & 1, nxt = cur ^ 1;
        if (tap < 8) LOADTAP(tap + 1, nxt);   // issue next-tap reads FIRST
        if (tap < 8)
          __builtin_amdgcn_sched_group_barrier(0x100, 6, 0);  // DS_READ x6 (t+1)
        __builtin_amdgcn_s_setprio(1);
        #pragma unroll
        for (int bt = 0; bt < 4; ++bt) {
          acc[0][bt] = __builtin_amdgcn_mfma_i32_32x32x32_i8(fa0[cur], fb[cur][bt], acc[0][bt], 0, 0, 0);
          acc[1][bt] = __builtin_amdgcn_mfma_i32_32x32x32_i8(fa1[cur], fb[cur][bt], acc[1][bt], 0, 0, 0);
        }
        __builtin_amdgcn_sched_group_barrier(0x008, 8, 0);    // MFMA x8 (tap t)
        __builtin_amdgcn_s_setprio(0);
      }
    }
    buf ^= 1;
  }

  const int h = h0 + 2 * wv + (n >> 4);   // <= 55 always
  const int wbase = lane & 15;
  #pragma unroll
  for (int ct = 0; ct < 2; ++ct) {
    #pragma unroll
    for (int r = 0; r < 16; ++r) {
      const int co64 = ct * 32 + (r & 3) + 8 * (r >> 2) + 4 * gq;
      const int bv = bls[co64];
      int* orow = out + ((b * 256 + tc * 64 + co64) * 56 + h) * 56;
      #pragma unroll
      for (int bt = 0; bt < 4; ++bt) {
        const int w0 = bt * 16 + wbase;
        if (w0 < 56) orow[w0] = acc[ct][bt][r] + bv;
      }
    }
  }
}

extern "C" void kernel_launch(void* const* d_in, const int* in_sizes, int n_in,
                              void* d_out, int out_size, void* d_ws, size_t ws_size,
                              hipStream_t stream) {
  const int* x    = (const int*)d_in[0];
  const int* w    = (const int*)d_in[1];
  const int* bias = (const int*)d_in[2];
  unsigned char* ws8 = (unsigned char*)d_ws;   // x8 then w8 (~14.4 MB)
  hipLaunchKernelGGL(pack_all, dim3(1156), dim3(256), 0, stream, x, w, ws8);
  hipLaunchKernelGGL(conv_main, dim3(112, 4, 1), dim3(256), 0, stream,
                     ws8, bias, (int*)d_out);
}